// Round 4
// baseline (231.834 us; speedup 1.0000x reference)
//
#include <hip/hip_runtime.h>
#include <math.h>

#define WIDTH 512
#define HALF  256
#define DEPTH 32
#define BATCH 65536
#define RPW   8   // rows per wave

// Precomputed per-(depth, physical position) parameters, stored in the
// physical order the main kernel reads them (coalesced):
//   entry index = d*512 + slot*64 + lane   for physical p = lane*8 + slot
// T1 = {A = a*cos(th), S = +-a*sin(th), B = sinh(bias), cc}
// T2 = invk = exp(-curv)
// One extra (garbage) layer of padding so the d=31 prefetch needs no guard.
__device__ float4 g_T1[(DEPTH + 1) * WIDTH];
__device__ float  g_T2[(DEPTH + 1) * WIDTH];

__global__ __launch_bounds__(256) void precompute_kernel(
    const float* __restrict__ thetas, const float* __restrict__ biases,
    const float* __restrict__ slopes1, const float* __restrict__ slopes2,
    const float* __restrict__ curvatures) {
  int tid = blockIdx.x * 256 + threadIdx.x;
  if (tid >= DEPTH * WIDTH) return;
  int d = tid >> 9;
  int p = tid & 511;
  // logical column of physical p AFTER layer d = rotl9(p, d+1)
  int rot = (d + 1) % 9;
  int j = ((p << rot) | (p >> (9 - rot))) & 511;
  int i = j >> 1;          // theta index
  int role = j & 1;        // 0 = n0 (x0*c + x1*s), 1 = n1 (-x0*s + x1*c)
  float th = thetas[d * HALF + i];
  float c = cosf(th), s = sinf(th);
  float m1 = expf(slopes1[d * WIDTH + j]);
  float m2 = expf(slopes2[d * WIDTH + j]);
  float a  = 0.5f * (m1 + m2);
  float cc = (m2 - m1) / (m1 + m2);   // (m2-m1)/(2a)
  float b  = sinhf(biases[d * WIDTH + j]);
  float invk = expf(-curvatures[d * WIDTH + j]);
  float A = a * c;
  float S = role ? (-a * s) : (a * s);
  int q = d * WIDTH + ((p & 7) * 64 + (p >> 3));  // physical storage order
  g_T1[q] = make_float4(A, S, b, cc);
  g_T2[q] = invk;
}

#if __has_builtin(__builtin_amdgcn_sqrtf)
#define FAST_SQRT(x) __builtin_amdgcn_sqrtf(x)
#else
#define FAST_SQRT(x) sqrtf(x)
#endif

// xor-exchange across lanes. Masks 1..16 stay within 32-lane groups ->
// ds_swizzle BitMode (no address VGPR): offset = (xor<<10)|0x1F.
// Mask 32 crosses the 32-lane boundary -> __shfl_xor.
template <int M>
__device__ __forceinline__ float xshfl(float v) {
  if constexpr (M < 32) {
    constexpr int ctl = (M << 10) | 0x1F;
    return __int_as_float(__builtin_amdgcn_ds_swizzle(__float_as_int(v), ctl));
  } else {
    return __shfl_xor(v, 32, 64);
  }
}

__device__ __forceinline__ float stepf(float xs, float v, float4 P, float ik) {
  float u = fmaf(xs, P.x, fmaf(v, P.y, -P.z));
  float t = fmaf(u, u, ik);
  return fmaf(P.w, FAST_SQRT(t), u);
}

// One layer. K = physical bit index this layer pairs on.
// K >= 3: cross-lane (xor mask 1<<(K-3)); K < 3: intra-thread slot pair.
// Rotating JIT prefetch: right after slot s (or pair) is computed with the
// in-register params, reload P[s]/IK[s] with layer d+1's slot-s params.
// Each load then has ~7 slots of compute before its first consumer.
template <int K>
__device__ __forceinline__ void layer_step(int d, int lane, float (&x)[8][RPW],
                                           float4 (&P)[8], float (&IK)[8]) {
  const float4* __restrict__ t1n = g_T1 + (d + 1) * WIDTH + lane;
  const float*  __restrict__ t2n = g_T2 + (d + 1) * WIDTH + lane;
  if constexpr (K >= 3) {
    constexpr int m = 1 << (K - 3);
#pragma unroll
    for (int s = 0; s < 8; ++s) {
      float4 Pc = P[s];
      float ikc = IK[s];
      P[s] = t1n[s * 64];   // prefetch layer d+1, slot s
      IK[s] = t2n[s * 64];
#pragma unroll
      for (int r = 0; r < RPW; ++r) {
        float xs = x[s][r];
        float v = xshfl<m>(xs);
        x[s][r] = stepf(xs, v, Pc, ikc);
      }
    }
  } else {
    constexpr int SX = 1 << K;
#pragma unroll
    for (int s0 = 0; s0 < 8; ++s0) {
      if (s0 & SX) continue;
      const int s1 = s0 | SX;
      float4 P0 = P[s0], P1 = P[s1];
      float ik0 = IK[s0], ik1 = IK[s1];
      P[s0] = t1n[s0 * 64]; IK[s0] = t2n[s0 * 64];   // prefetch d+1
      P[s1] = t1n[s1 * 64]; IK[s1] = t2n[s1 * 64];
#pragma unroll
      for (int r = 0; r < RPW; ++r) {
        float v0 = x[s0][r], v1 = x[s1][r];
        float n0 = stepf(v0, v1, P0, ik0);
        float n1 = stepf(v1, v0, P1, ik1);
        x[s0][r] = n0;
        x[s1][r] = n1;
      }
    }
  }
}

__global__ __launch_bounds__(256, 4) void net_kernel(const float* __restrict__ X,
                                                     float* __restrict__ out) {
  const int lane = threadIdx.x & 63;
  const int wv = blockIdx.x * 4 + (threadIdx.x >> 6);
  const size_t row0 = (size_t)wv * RPW;

  // physical position of x[s][r] within the row: p = lane*8 + s
  float x[8][RPW];
  const float4* __restrict__ Xv =
      reinterpret_cast<const float4*>(X + row0 * WIDTH);
#pragma unroll
  for (int r = 0; r < RPW; ++r) {
    float4 a = Xv[r * (WIDTH / 4) + lane * 2];
    float4 b = Xv[r * (WIDTH / 4) + lane * 2 + 1];
    x[0][r] = a.x; x[1][r] = a.y; x[2][r] = a.z; x[3][r] = a.w;
    x[4][r] = b.x; x[5][r] = b.y; x[6][r] = b.z; x[7][r] = b.w;
  }

  // initial params (layer 0)
  float4 P[8];
  float IK[8];
#pragma unroll
  for (int s = 0; s < 8; ++s) {
    P[s] = g_T1[s * 64 + lane];
    IK[s] = g_T2[s * 64 + lane];
  }

  // layer d pairs on physical bit k = 8 - (d % 9); pattern period 9
#define RUN_LAYER(DD)                                 \
  do {                                                \
    if (d0 + DD < DEPTH) {                            \
      layer_step<8 - DD>(d0 + DD, lane, x, P, IK);    \
    }                                                 \
  } while (0)

#pragma unroll 1
  for (int d0 = 0; d0 < DEPTH; d0 += 9) {
    RUN_LAYER(0); RUN_LAYER(1); RUN_LAYER(2);
    RUN_LAYER(3); RUN_LAYER(4); RUN_LAYER(5);
    RUN_LAYER(6); RUN_LAYER(7); RUN_LAYER(8);
  }
#undef RUN_LAYER

  // final logical column of physical p is rotl9(p, 32 mod 9 = 5)
  float* __restrict__ O = out + row0 * WIDTH;
#pragma unroll
  for (int s = 0; s < 8; ++s) {
    const int p = lane * 8 + s;
    const int cfin = ((p << 5) | (p >> 4)) & 511;
#pragma unroll
    for (int r = 0; r < RPW; ++r) O[r * WIDTH + cfin] = x[s][r];
  }
}

extern "C" void kernel_launch(void* const* d_in, const int* in_sizes, int n_in,
                              void* d_out, int out_size, void* d_ws, size_t ws_size,
                              hipStream_t stream) {
  const float* X          = (const float*)d_in[0];
  const float* thetas     = (const float*)d_in[1];
  const float* biases     = (const float*)d_in[2];
  const float* slopes1    = (const float*)d_in[3];
  const float* slopes2    = (const float*)d_in[4];
  const float* curvatures = (const float*)d_in[5];
  float* out = (float*)d_out;

  hipLaunchKernelGGL(precompute_kernel, dim3((DEPTH * WIDTH + 255) / 256),
                     dim3(256), 0, stream, thetas, biases, slopes1, slopes2,
                     curvatures);
  hipLaunchKernelGGL(net_kernel, dim3(BATCH / (RPW * 4)), dim3(256), 0, stream,
                     X, out);
}

// Round 5
// 201.586 us; speedup vs baseline: 1.1501x; 1.1501x over previous
//
#include <hip/hip_runtime.h>
#include <math.h>

#define WIDTH 512
#define HALF  256
#define DEPTH 32
#define BATCH 65536
#define RPW   8   // rows per row-group (one 2-wave block)
#define NS    4   // slots (physical bits 0-1) per thread

// Precomputed per-(depth, physical position) parameters, stored in the order
// the main kernel reads them (coalesced):
//   storage idx = d*512 + w*256 + s*64 + lane,  physical p = w*256 + lane*4 + s
// T1 = {A = a*cos(th), S = +-a*sin(th), B = sinh(bias), cc} ; T2 = exp(-curv)
__device__ float4 g_T1[DEPTH * WIDTH];
__device__ float  g_T2[DEPTH * WIDTH];

__global__ __launch_bounds__(256) void precompute_kernel(
    const float* __restrict__ thetas, const float* __restrict__ biases,
    const float* __restrict__ slopes1, const float* __restrict__ slopes2,
    const float* __restrict__ curvatures) {
  int tid = blockIdx.x * 256 + threadIdx.x;
  if (tid >= DEPTH * WIDTH) return;
  int d = tid >> 9;
  int idx = tid & 511;
  int w = idx >> 8, s = (idx >> 6) & 3, l = idx & 63;
  int p = w * 256 + l * 4 + s;
  // logical column of physical p AFTER layer d = rotl9(p, d+1)
  int rot = (d + 1) % 9;
  int j = ((p << rot) | (p >> (9 - rot))) & 511;
  int i = j >> 1;          // theta index
  int role = j & 1;        // 0 = n0 (x0*c + x1*s), 1 = n1 (-x0*s + x1*c)
  float th = thetas[d * HALF + i];
  float c = cosf(th), sn = sinf(th);
  float m1 = expf(slopes1[d * WIDTH + j]);
  float m2 = expf(slopes2[d * WIDTH + j]);
  float a  = 0.5f * (m1 + m2);
  float cc = (m2 - m1) / (m1 + m2);   // (m2-m1)/(2a)
  float b  = sinhf(biases[d * WIDTH + j]);
  float ik = expf(-curvatures[d * WIDTH + j]);
  float A = a * c;
  float S = role ? (-a * sn) : (a * sn);
  g_T1[d * WIDTH + idx] = make_float4(A, S, b, cc);
  g_T2[d * WIDTH + idx] = ik;
}

#if __has_builtin(__builtin_amdgcn_sqrtf)
#define FAST_SQRT(x) __builtin_amdgcn_sqrtf(x)
#else
#define FAST_SQRT(x) sqrtf(x)
#endif

// xor-exchange across lanes. Masks 1..16 stay within 32-lane groups ->
// ds_swizzle BitMode (no address VGPR): offset = (xor<<10)|0x1F.
// Mask 32 crosses the 32-lane boundary -> __shfl_xor.
template <int M>
__device__ __forceinline__ float xshfl(float v) {
  if constexpr (M < 32) {
    constexpr int ctl = (M << 10) | 0x1F;
    return __int_as_float(__builtin_amdgcn_ds_swizzle(__float_as_int(v), ctl));
  } else {
    return __shfl_xor(v, 32, 64);
  }
}

__device__ __forceinline__ float stepf(float xs, float v, float4 P, float ik) {
  float u = fmaf(xs, P.x, fmaf(v, P.y, -P.z));
  float t = fmaf(u, u, ik);
  return fmaf(P.w, FAST_SQRT(t), u);
}

// One layer pairing on physical bit K.
//  K == 8   : cross-wave exchange through LDS (write all, barrier, read partner)
//  K in 2..7: cross-lane xor (mask 1<<(K-2))
//  K in 0..1: intra-thread slot pair
// t1/t2 pre-offset to d*512 + w*256 + lane; slot s at +s*64.
template <int K>
__device__ __forceinline__ void layer_step(const float4* __restrict__ t1,
                                           const float* __restrict__ t2,
                                           float (&x)[NS][RPW], float* xb,
                                           int tid) {
  if constexpr (K == 8) {
#pragma unroll
    for (int s = 0; s < NS; ++s)
#pragma unroll
      for (int r = 0; r < RPW; ++r)
        xb[(s * RPW + r) * 128 + tid] = x[s][r];
    __syncthreads();
    const int pt = tid ^ 64;  // partner wave, same lane
#pragma unroll
    for (int s = 0; s < NS; ++s) {
      float4 P = t1[s * 64];
      float ik = t2[s * 64];
      float v[RPW];
#pragma unroll
      for (int r = 0; r < RPW; ++r) v[r] = xb[(s * RPW + r) * 128 + pt];
#pragma unroll
      for (int r = 0; r < RPW; ++r) x[s][r] = stepf(x[s][r], v[r], P, ik);
    }
    __syncthreads();  // protect xb before next exchange's writes
  } else if constexpr (K >= 2) {
    constexpr int m = 1 << (K - 2);
#pragma unroll
    for (int s = 0; s < NS; ++s) {
      float4 P = t1[s * 64];
      float ik = t2[s * 64];
#pragma unroll
      for (int r = 0; r < RPW; ++r) {
        float xs = x[s][r];
        float v = xshfl<m>(xs);
        x[s][r] = stepf(xs, v, P, ik);
      }
    }
  } else {
    constexpr int SX = 1 << K;
#pragma unroll
    for (int s0 = 0; s0 < NS; ++s0) {
      if (s0 & SX) continue;
      const int s1 = s0 | SX;
      float4 P0 = t1[s0 * 64];
      float ik0 = t2[s0 * 64];
      float4 P1 = t1[s1 * 64];
      float ik1 = t2[s1 * 64];
#pragma unroll
      for (int r = 0; r < RPW; ++r) {
        float v0 = x[s0][r], v1 = x[s1][r];
        float n0 = stepf(v0, v1, P0, ik0);
        float n1 = stepf(v1, v0, P1, ik1);
        x[s0][r] = n0;
        x[s1][r] = n1;
      }
    }
  }
}

__global__ __launch_bounds__(128, 4) void net_kernel(const float* __restrict__ X,
                                                     float* __restrict__ out) {
  __shared__ float xb[NS * RPW * 128];  // 16 KB: [elem e][tid]
  const int tid = threadIdx.x;          // 0..127 (2 waves)
  const int lane = tid & 63;
  const int w = tid >> 6;               // physical bit 8
  const size_t row0 = (size_t)blockIdx.x * RPW;

  // thread's physical positions: p = w*256 + lane*4 + s, s = 0..3
  float x[NS][RPW];
  const float* __restrict__ Xp = X + row0 * WIDTH + w * 256 + lane * 4;
#pragma unroll
  for (int r = 0; r < RPW; ++r) {
    float4 a = *reinterpret_cast<const float4*>(Xp + (size_t)r * WIDTH);
    x[0][r] = a.x; x[1][r] = a.y; x[2][r] = a.z; x[3][r] = a.w;
  }

  const int poff = w * 256 + lane;
  // layer d pairs on physical bit k = 8 - (d % 9); pattern period 9
#define RUN_LAYER(DD)                                                    \
  do {                                                                   \
    if (d0 + DD < DEPTH) {                                               \
      layer_step<8 - DD>(g_T1 + (d0 + DD) * WIDTH + poff,                \
                         g_T2 + (d0 + DD) * WIDTH + poff, x, xb, tid);   \
    }                                                                    \
  } while (0)

#pragma unroll 1
  for (int d0 = 0; d0 < DEPTH; d0 += 9) {
    RUN_LAYER(0); RUN_LAYER(1); RUN_LAYER(2);
    RUN_LAYER(3); RUN_LAYER(4); RUN_LAYER(5);
    RUN_LAYER(6); RUN_LAYER(7); RUN_LAYER(8);
  }
#undef RUN_LAYER

  // final logical column of physical p is rotl9(p, 32 mod 9 = 5)
  float* __restrict__ O = out + row0 * WIDTH;
#pragma unroll
  for (int s = 0; s < NS; ++s) {
    const int p = w * 256 + lane * 4 + s;
    const int cfin = ((p << 5) | (p >> 4)) & 511;
#pragma unroll
    for (int r = 0; r < RPW; ++r) O[r * WIDTH + cfin] = x[s][r];
  }
}

extern "C" void kernel_launch(void* const* d_in, const int* in_sizes, int n_in,
                              void* d_out, int out_size, void* d_ws, size_t ws_size,
                              hipStream_t stream) {
  const float* X          = (const float*)d_in[0];
  const float* thetas     = (const float*)d_in[1];
  const float* biases     = (const float*)d_in[2];
  const float* slopes1    = (const float*)d_in[3];
  const float* slopes2    = (const float*)d_in[4];
  const float* curvatures = (const float*)d_in[5];
  float* out = (float*)d_out;

  hipLaunchKernelGGL(precompute_kernel, dim3((DEPTH * WIDTH + 255) / 256),
                     dim3(256), 0, stream, thetas, biases, slopes1, slopes2,
                     curvatures);
  hipLaunchKernelGGL(net_kernel, dim3(BATCH / RPW), dim3(128), 0, stream,
                     X, out);
}